// Round 16
// baseline (2329.910 us; speedup 1.0000x reference)
//
#include <hip/hip_runtime.h>

#define BB   64
#define PP   196
#define ENCD 2048
#define DECD 512
#define VV   10000
#define TT   21
#define KIH  2560   // (EMB + ENC) rows of W_ih

typedef __attribute__((ext_vector_type(8))) short bf16x8;
typedef __attribute__((ext_vector_type(4))) float f32x4;
typedef float f32x2 __attribute__((ext_vector_type(2)));

__device__ __forceinline__ float sigm(float x)   { return 1.f / (1.f + __expf(-x)); }
__device__ __forceinline__ float tanh_f(float x) { return 1.f - 2.f / (1.f + __expf(2.f * x)); }
__device__ __forceinline__ ushort f2bf(float x) {
    unsigned u = __float_as_uint(x);
    unsigned r = (u + 0x7FFFu + ((u >> 16) & 1u)) >> 16;
    return (ushort)r;
}
__device__ __forceinline__ float bf2f(ushort u) {
    return __uint_as_float(((unsigned)u) << 16);
}
union U8 { float4 f4; ushort u[8]; };

// ---- fp8 helpers (HW cvt when available; self-consistent SW fallback) ----
#if __has_builtin(__builtin_amdgcn_cvt_pk_fp8_f32) && __has_builtin(__builtin_amdgcn_cvt_pk_f32_fp8)
#define HAVE_HW_FP8 1
#endif

__device__ uint enc8m(float x) {     // e4m3fn round-to-nearest (fallback only)
    uint s = (__float_as_uint(x) >> 31) << 7;
    float ax = fabsf(x);
    if (!(ax > 0.f)) return s;
    if (ax >= 448.f) return s | 0x7e;
    int e; float m = frexpf(ax, &e);
    int E = e - 1 + 7;
    if (E <= 0) { int q = (int)rintf(ax * 512.f); if (q > 7) return s | 0x08; return s | (uint)q; }
    int q = (int)rintf((m * 2.f - 1.f) * 8.f);
    if (q == 8) { q = 0; ++E; if (E > 15) return s | 0x7e; }
    return s | ((uint)E << 3) | (uint)q;
}
__device__ __forceinline__ float dec8m(uint b) {
    uint s = b >> 7, e = (b >> 3) & 15, m = b & 7;
    float v = (e == 0) ? (float)m * (1.f / 512.f) : ldexpf(1.f + (float)m * 0.125f, (int)e - 7);
    return s ? -v : v;
}
__device__ __forceinline__ uint pkfp8x4(float a, float b, float c, float d) {
#ifdef HAVE_HW_FP8
    int v = __builtin_amdgcn_cvt_pk_fp8_f32(a, b, 0, false);
    v = __builtin_amdgcn_cvt_pk_fp8_f32(c, d, v, true);
    return (uint)v;
#else
    return enc8m(a) | (enc8m(b) << 8) | (enc8m(c) << 16) | (enc8m(d) << 24);
#endif
}
__device__ __forceinline__ void dec8x4(uint v, float out[4]) {
#ifdef HAVE_HW_FP8
    f32x2 lo = __builtin_amdgcn_cvt_pk_f32_fp8((int)v, false);
    f32x2 hi = __builtin_amdgcn_cvt_pk_f32_fp8((int)v, true);
    out[0] = lo[0]; out[1] = lo[1]; out[2] = hi[0]; out[3] = hi[1];
#else
    out[0] = dec8m(v & 255); out[1] = dec8m((v >> 8) & 255);
    out[2] = dec8m((v >> 16) & 255); out[3] = dec8m(v >> 24);
#endif
}

// ---------------- setup kernels ----------------

// fused: f32 -> bf16 AND fp8x4 in one pass over enc
__global__ void k_cvt2(const float* __restrict__ in, ushort* __restrict__ outB,
                       uint* __restrict__ out8, int n4) {
    int i = blockIdx.x * 256 + threadIdx.x;
    if (i >= n4) return;
    float4 v = ((const float4*)in)[i];
    ushort4 o; o.x = f2bf(v.x); o.y = f2bf(v.y); o.z = f2bf(v.z); o.w = f2bf(v.w);
    ((ushort4*)outB)[i] = o;
    out8[i] = pkfp8x4(v.x, v.y, v.z, v.w);
}

__global__ void k_mean16(const ushort* __restrict__ encB, float* __restrict__ mean) {
    int idx = blockIdx.x * 256 + threadIdx.x;
    int b = idx >> 10, e2 = idx & 1023;
    const uint* p = (const uint*)encB + (size_t)b * PP * 1024 + e2;
    float s0 = 0.f, s1 = 0.f;
    #pragma unroll 7
    for (int i = 0; i < PP; ++i) {
        uint v = p[(size_t)i * 1024];
        s0 += __uint_as_float(v << 16);
        s1 += __uint_as_float(v & 0xffff0000u);
    }
    mean[b * 2048 + e2 * 2]     = s0 * (1.f / 196.f);
    mean[b * 2048 + e2 * 2 + 1] = s1 * (1.f / 196.f);
}

__global__ __launch_bounds__(256) void k_ipart(const float* __restrict__ mean,
        const float* __restrict__ Wh, const float* __restrict__ Wc,
        float* __restrict__ ipart) {
    __shared__ alignas(16) float As[32][68];
    __shared__ alignas(16) float Bs[32][68];
    const int n0 = blockIdx.x * 64;
    const int kc = blockIdx.y;
    const int mat = blockIdx.z;
    const float* Bp = mat ? Wc : Wh;
    const int tid = threadIdx.x, tx = tid & 15, ty = tid >> 4;
    float acc[4][4] = {};
    for (int k0 = 0; k0 < 512; k0 += 32) {
        #pragma unroll
        for (int p = 0; p < 2; ++p) {
            int c = p * 256 + tid;
            int m = c >> 3, k4 = (c & 7) * 4;
            float4 v = *(const float4*)(mean + m * 2048 + kc * 512 + k0 + k4);
            As[k4 + 0][m] = v.x; As[k4 + 1][m] = v.y; As[k4 + 2][m] = v.z; As[k4 + 3][m] = v.w;
            int kb = c >> 4, n4 = (c & 15) * 4;
            float4 w = *(const float4*)(Bp + (size_t)(kc * 512 + k0 + kb) * 512 + n0 + n4);
            *(float4*)&Bs[kb][n4] = w;
        }
        __syncthreads();
        #pragma unroll 8
        for (int k = 0; k < 32; ++k) {
            float4 a = *(const float4*)&As[k][ty * 4];
            float4 b = *(const float4*)&Bs[k][tx * 4];
            float av[4] = {a.x, a.y, a.z, a.w}, bv[4] = {b.x, b.y, b.z, b.w};
            #pragma unroll
            for (int i = 0; i < 4; ++i)
                #pragma unroll
                for (int j = 0; j < 4; ++j) acc[i][j] += av[i] * bv[j];
        }
        __syncthreads();
    }
    #pragma unroll
    for (int i = 0; i < 4; ++i) {
        int m = ty * 4 + i;
        #pragma unroll
        for (int j = 0; j < 4; ++j) {
            int n = n0 + tx * 4 + j;
            ipart[((size_t)(mat * 4 + kc) * BB + m) * 512 + n] = acc[i][j];
        }
    }
}

__global__ void k_ifin(const float* __restrict__ ipart,
                       const float* __restrict__ bh, const float* __restrict__ bc,
                       float* __restrict__ h, float* __restrict__ c, ushort* __restrict__ hB) {
    int idx = blockIdx.x * 256 + threadIdx.x;
    int mat = idx >> 15, rem = idx & 32767;
    int b = rem >> 9, d = rem & 511;
    float s = 0.f;
    #pragma unroll
    for (int kc = 0; kc < 4; ++kc) s += ipart[((size_t)(mat * 4 + kc) * BB + b) * 512 + d];
    if (mat) c[rem] = s + bc[d];
    else { float v = s + bh[d]; h[rem] = v; hB[rem] = f2bf(v); }
}

__global__ __launch_bounds__(256) void k_tcvt_all(
        const float* __restrict__ Wenc, const float* __restrict__ Wdec,
        const float* __restrict__ Wbeta, const float* __restrict__ Whh,
        const float* __restrict__ Wih, const float* __restrict__ Wfc,
        ushort* __restrict__ WencT, ushort* __restrict__ WdecT,
        ushort* __restrict__ WbetaT, ushort* __restrict__ WhhT,
        ushort* __restrict__ WihT, ushort* __restrict__ WfcT) {
    __shared__ float lds[64 * 65];
    int l = blockIdx.x;
    const float* in; ushort* out; int K, N, KT;
    if (l < 256)       { in = Wenc;  out = WencT;  K = 2048; N = 512;   KT = 32; }
    else if (l < 320)  { l -= 256;  in = Wdec;  out = WdecT;  K = 512;  N = 512;   KT = 8; }
    else if (l < 576)  { l -= 320;  in = Wbeta; out = WbetaT; K = 512;  N = 2048;  KT = 8; }
    else if (l < 832)  { l -= 576;  in = Whh;   out = WhhT;   K = 512;  N = 2048;  KT = 8; }
    else if (l < 2112) { l -= 832;  in = Wih;   out = WihT;   K = KIH;  N = 2048;  KT = 40; }
    else               { l -= 2112; in = Wfc;   out = WfcT;   K = 512;  N = 10000; KT = 8; }
    const int k0 = (l % KT) * 64, n0 = (l / KT) * 64;
    const int tid = threadIdx.x;
    for (int i = tid; i < 4096; i += 256) {
        int kk = i >> 6, nn = i & 63;
        float v = 0.f;
        if (n0 + nn < N) v = in[(size_t)(k0 + kk) * N + n0 + nn];
        lds[nn * 65 + kk] = v;
    }
    __syncthreads();
    for (int i = tid; i < 4096; i += 256) {
        int nn = i >> 6, kk = i & 63;
        out[(size_t)(n0 + nn) * K + k0 + kk] = f2bf(lds[nn * 65 + kk]);
    }
}

// att1B[12544][512] bf16 = bf16(encB @ WencT^T + bias). grid (2, 196)
__global__ __launch_bounds__(256) void k_att1n(const ushort* __restrict__ A,
        const ushort* __restrict__ Bt, const float* __restrict__ bias,
        ushort* __restrict__ C) {
    __shared__ alignas(16) ushort As[64 * 64];
    __shared__ alignas(16) ushort Bs[256 * 64];
    const int n0 = blockIdx.x * 256;
    const int m0 = blockIdx.y * 64;
    const int tid = threadIdx.x, wid = tid >> 6, lane = tid & 63;
    f32x4 acc[4][4] = {};
    for (int k0 = 0; k0 < 2048; k0 += 64) {
        #pragma unroll
        for (int p = 0; p < 2; ++p) {
            int c = p * 256 + tid;
            int r = c >> 3, cc = c & 7;
            float4 v = *(const float4*)(A + (size_t)(m0 + r) * 2048 + k0 + cc * 8);
            *(float4*)(As + r * 64 + ((cc ^ (r & 7)) * 8)) = v;
        }
        #pragma unroll
        for (int p = 0; p < 8; ++p) {
            int c = p * 256 + tid;
            int r = c >> 3, cc = c & 7;
            float4 v = *(const float4*)(Bt + (size_t)(n0 + r) * 2048 + k0 + cc * 8);
            *(float4*)(Bs + r * 64 + ((cc ^ (r & 7)) * 8)) = v;
        }
        __syncthreads();
        #pragma unroll
        for (int kk = 0; kk < 2; ++kk) {
            int ci = kk * 4 + (lane >> 4);
            bf16x8 afrag[4], bfrag[4];
            #pragma unroll
            for (int m = 0; m < 4; ++m) {
                int row = m * 16 + (lane & 15);
                afrag[m] = *(const bf16x8*)(As + row * 64 + ((ci ^ (row & 7)) * 8));
            }
            #pragma unroll
            for (int n = 0; n < 4; ++n) {
                int col = wid * 64 + n * 16 + (lane & 15);
                bfrag[n] = *(const bf16x8*)(Bs + col * 64 + ((ci ^ (col & 7)) * 8));
            }
            #pragma unroll
            for (int m = 0; m < 4; ++m)
                #pragma unroll
                for (int n = 0; n < 4; ++n)
                    acc[m][n] = __builtin_amdgcn_mfma_f32_16x16x32_bf16(afrag[m], bfrag[n], acc[m][n], 0, 0, 0);
        }
        __syncthreads();
    }
    #pragma unroll
    for (int m = 0; m < 4; ++m) {
        int rb = m0 + m * 16 + (lane >> 4) * 4;
        #pragma unroll
        for (int n = 0; n < 4; ++n) {
            int col = n0 + wid * 64 + n * 16 + (lane & 15);
            float bv = bias[col];
            #pragma unroll
            for (int r = 0; r < 4; ++r)
                C[(size_t)(rb + r) * 512 + col] = f2bf(acc[m][n][r] + bv);
        }
    }
}

// xpre[t][b][2048] = emb[caps[b,t]] @ W_ih[0:512]. grid (8, 21)
__global__ __launch_bounds__(256) void k_xpre(const float* __restrict__ emb,
        const int* __restrict__ caps, const ushort* __restrict__ WihT,
        float* __restrict__ xpre) {
    __shared__ alignas(16) ushort As[64 * 64];
    __shared__ alignas(16) ushort Bs[256 * 64];
    __shared__ int capsh[64];
    const int n0 = blockIdx.x * 256;
    const int t = blockIdx.y;
    const int tid = threadIdx.x, wid = tid >> 6, lane = tid & 63;
    if (tid < 64) capsh[tid] = caps[tid * 22 + t];
    __syncthreads();
    f32x4 acc[4][4] = {};
    for (int k0 = 0; k0 < 512; k0 += 64) {
        #pragma unroll
        for (int p = 0; p < 2; ++p) {
            int c = p * 256 + tid;
            int r = c >> 3, cc = c & 7;
            const float* er = emb + (size_t)capsh[r] * 512 + k0 + cc * 8;
            float4 v0 = *(const float4*)er;
            float4 v1 = *(const float4*)(er + 4);
            U8 pk;
            pk.u[0] = f2bf(v0.x); pk.u[1] = f2bf(v0.y); pk.u[2] = f2bf(v0.z); pk.u[3] = f2bf(v0.w);
            pk.u[4] = f2bf(v1.x); pk.u[5] = f2bf(v1.y); pk.u[6] = f2bf(v1.z); pk.u[7] = f2bf(v1.w);
            *(float4*)(As + r * 64 + ((cc ^ (r & 7)) * 8)) = pk.f4;
        }
        #pragma unroll
        for (int p = 0; p < 8; ++p) {
            int c = p * 256 + tid;
            int r = c >> 3, cc = c & 7;
            float4 v = *(const float4*)(WihT + (size_t)(n0 + r) * KIH + k0 + cc * 8);
            *(float4*)(Bs + r * 64 + ((cc ^ (r & 7)) * 8)) = v;
        }
        __syncthreads();
        #pragma unroll
        for (int kk = 0; kk < 2; ++kk) {
            int ci = kk * 4 + (lane >> 4);
            bf16x8 afrag[4], bfrag[4];
            #pragma unroll
            for (int m = 0; m < 4; ++m) {
                int row = m * 16 + (lane & 15);
                afrag[m] = *(const bf16x8*)(As + row * 64 + ((ci ^ (row & 7)) * 8));
            }
            #pragma unroll
            for (int n = 0; n < 4; ++n) {
                int col = wid * 64 + n * 16 + (lane & 15);
                bfrag[n] = *(const bf16x8*)(Bs + col * 64 + ((ci ^ (col & 7)) * 8));
            }
            #pragma unroll
            for (int m = 0; m < 4; ++m)
                #pragma unroll
                for (int n = 0; n < 4; ++n)
                    acc[m][n] = __builtin_amdgcn_mfma_f32_16x16x32_bf16(afrag[m], bfrag[n], acc[m][n], 0, 0, 0);
        }
        __syncthreads();
    }
    #pragma unroll
    for (int m = 0; m < 4; ++m) {
        int rb = m * 16 + (lane >> 4) * 4;
        #pragma unroll
        for (int n = 0; n < 4; ++n) {
            int col = n0 + wid * 64 + n * 16 + (lane & 15);
            #pragma unroll
            for (int r = 0; r < 4; ++r)
                xpre[((size_t)t * BB + rb + r) * 2048 + col] = acc[m][n][r];
        }
    }
}

__global__ void k_declen(const int* __restrict__ lens, float* __restrict__ out) {
    int b = threadIdx.x;
    if (b < BB) out[b] = (float)(lens[b] - 1);
}

// ---------------- per-step kernels ----------------

// P1: att2|gate|hhp = hB @ WcatT (72 tiles of 64 cols, K=512)
__global__ __launch_bounds__(256) void k_p1(const ushort* __restrict__ hB,
        const ushort* __restrict__ WcatT, const float* __restrict__ bd,
        const float* __restrict__ bb, float* __restrict__ att2,
        float* __restrict__ gate, float* __restrict__ hhp) {
    __shared__ alignas(16) ushort As[64 * 64];
    __shared__ alignas(16) ushort Bs[64 * 64];
    const int tid = threadIdx.x, lane = tid & 63, wid = tid >> 6;
    const int n0 = blockIdx.x * 64;
    f32x4 acc[4] = {};
    for (int k0 = 0; k0 < 512; k0 += 64) {
        #pragma unroll
        for (int p = 0; p < 2; ++p) {
            int c8 = p * 256 + tid;
            int r = c8 >> 3, cc = c8 & 7;
            float4 v = *(const float4*)(hB + r * 512 + k0 + cc * 8);
            *(float4*)(As + r * 64 + ((cc ^ (r & 7)) * 8)) = v;
            float4 w = *(const float4*)(WcatT + (size_t)(n0 + r) * 512 + k0 + cc * 8);
            *(float4*)(Bs + r * 64 + ((cc ^ (r & 7)) * 8)) = w;
        }
        __syncthreads();
        #pragma unroll
        for (int kk = 0; kk < 2; ++kk) {
            int ci = kk * 4 + (lane >> 4);
            int colL = wid * 16 + (lane & 15);
            bf16x8 bfrag = *(const bf16x8*)(Bs + colL * 64 + ((ci ^ (colL & 7)) * 8));
            #pragma unroll
            for (int m = 0; m < 4; ++m) {
                int row = m * 16 + (lane & 15);
                bf16x8 afrag = *(const bf16x8*)(As + row * 64 + ((ci ^ (row & 7)) * 8));
                acc[m] = __builtin_amdgcn_mfma_f32_16x16x32_bf16(afrag, bfrag, acc[m], 0, 0, 0);
            }
        }
        __syncthreads();
    }
    int col = n0 + wid * 16 + (lane & 15);
    #pragma unroll
    for (int m = 0; m < 4; ++m) {
        int rb = m * 16 + (lane >> 4) * 4;
        #pragma unroll
        for (int r = 0; r < 4; ++r) {
            int row = rb + r;
            float v = acc[m][r];
            if (col < 512)       att2[row * 512 + col] = v + bd[col];
            else if (col < 2560) gate[row * 2048 + (col - 512)] = sigm(v + bb[col - 512]);
            else                 hhp[(size_t)row * 2048 + (col - 2560)] = v;
        }
    }
}

// P2 fused: e-scores + softmax + awe(fp8) + gate + pack; one block per b (64 blocks)
__global__ __launch_bounds__(256) void k_esawe(const ushort* __restrict__ att1B,
        const float* __restrict__ att2, const float* __restrict__ Wf,
        const uint* __restrict__ enc8, const float* __restrict__ gate,
        const int* __restrict__ lens, int t,
        uint* __restrict__ aweB, float* __restrict__ alpha_out) {
    __shared__ float a2[512], wf[512], als[224], red[256];
    const int b = blockIdx.x, tid = threadIdx.x;
    const int lane = tid & 63, wid = tid >> 6;
    for (int i = tid; i < 512; i += 256) { a2[i] = att2[b * 512 + i]; wf[i] = Wf[i]; }
    __syncthreads();
    // e-scores: wave per row, 49 rows/wave
    for (int p = wid; p < PP; p += 4) {
        bf16x8 rv = *(const bf16x8*)(att1B + ((size_t)(b * PP + p)) * 512 + lane * 8);
        float s = 0.f;
        #pragma unroll
        for (int j = 0; j < 8; ++j) {
            float v = bf2f((ushort)rv[j]) + a2[lane * 8 + j];
            s += (v > 0.f ? v : 0.f) * wf[lane * 8 + j];
        }
        #pragma unroll
        for (int off = 32; off; off >>= 1) s += __shfl_down(s, off);
        if (lane == 0) als[p] = s;
    }
    __syncthreads();
    // softmax over 196
    float v = (tid < PP) ? als[tid] : -3.4e38f;
    red[tid] = v; __syncthreads();
    for (int s = 128; s; s >>= 1) { if (tid < s) red[tid] = fmaxf(red[tid], red[tid + s]); __syncthreads(); }
    float mx = red[0]; __syncthreads();
    float ev = (tid < PP) ? __expf(v - mx) : 0.f;
    red[tid] = ev; __syncthreads();
    for (int s = 128; s; s >>= 1) { if (tid < s) red[tid] += red[tid + s]; __syncthreads(); }
    float inv = 1.f / red[0];
    if (tid < PP) {
        float a = ev * inv;
        als[tid] = a;
        bool m = t < (lens[b] - 1);
        alpha_out[((size_t)b * TT + t) * PP + tid] = m ? a : 0.f;
    }
    __syncthreads();
    // awe: 512 quads, 2 per thread (q = tid, tid+256)
    const uint* pp = enc8 + (size_t)b * PP * 512;
    float s0 = 0.f, s1 = 0.f, s2 = 0.f, s3 = 0.f;
    float r0 = 0.f, r1 = 0.f, r2 = 0.f, r3 = 0.f;
    #pragma unroll 4
    for (int p = 0; p < PP; ++p) {
        uint va = pp[(size_t)p * 512 + tid];
        uint vb = pp[(size_t)p * 512 + tid + 256];
        float a = als[p];
        float da[4], db[4];
        dec8x4(va, da); dec8x4(vb, db);
        s0 += a * da[0]; s1 += a * da[1]; s2 += a * da[2]; s3 += a * da[3];
        r0 += a * db[0]; r1 += a * db[1]; r2 += a * db[2]; r3 += a * db[3];
    }
    {
        int e = tid * 4;
        float g0 = s0 * gate[b * 2048 + e + 0];
        float g1 = s1 * gate[b * 2048 + e + 1];
        float g2 = s2 * gate[b * 2048 + e + 2];
        float g3 = s3 * gate[b * 2048 + e + 3];
        aweB[b * 1024 + tid * 2]     = (uint)f2bf(g0) | ((uint)f2bf(g1) << 16);
        aweB[b * 1024 + tid * 2 + 1] = (uint)f2bf(g2) | ((uint)f2bf(g3) << 16);
        int q2 = tid + 256;
        int e2 = q2 * 4;
        float h0 = r0 * gate[b * 2048 + e2 + 0];
        float h1 = r1 * gate[b * 2048 + e2 + 1];
        float h2 = r2 * gate[b * 2048 + e2 + 2];
        float h3 = r3 * gate[b * 2048 + e2 + 3];
        aweB[b * 1024 + q2 * 2]     = (uint)f2bf(h0) | ((uint)f2bf(h1) << 16);
        aweB[b * 1024 + q2 * 2 + 1] = (uint)f2bf(h2) | ((uint)f2bf(h3) << 16);
    }
}

// P3: pawe[kc] = aweB slice @ W_ih slice; grid 128
__global__ __launch_bounds__(256) void k_p3(const uint* __restrict__ aweB,
        const ushort* __restrict__ WihT, float* __restrict__ pawe) {
    __shared__ alignas(16) ushort As[64 * 64];
    __shared__ alignas(16) ushort Bs[64 * 64];
    const int tid = threadIdx.x, lane = tid & 63, wid = tid >> 6;
    const int n0 = (blockIdx.x & 31) * 64, kc = blockIdx.x >> 5;
    const ushort* aweU = (const ushort*)aweB;
    f32x4 acc[4] = {};
    for (int k0 = 0; k0 < 512; k0 += 64) {
        #pragma unroll
        for (int p = 0; p < 2; ++p) {
            int c8 = p * 256 + tid;
            int r = c8 >> 3, cc = c8 & 7;
            float4 v = *(const float4*)(aweU + r * 2048 + kc * 512 + k0 + cc * 8);
            *(float4*)(As + r * 64 + ((cc ^ (r & 7)) * 8)) = v;
            float4 w = *(const float4*)(WihT + (size_t)(n0 + r) * KIH + 512 + kc * 512 + k0 + cc * 8);
            *(float4*)(Bs + r * 64 + ((cc ^ (r & 7)) * 8)) = w;
        }
        __syncthreads();
        #pragma unroll
        for (int kk = 0; kk < 2; ++kk) {
            int ci = kk * 4 + (lane >> 4);
            int colL = wid * 16 + (lane & 15);
            bf16x8 bfrag = *(const bf16x8*)(Bs + colL * 64 + ((ci ^ (colL & 7)) * 8));
            #pragma unroll
            for (int m = 0; m < 4; ++m) {
                int row = m * 16 + (lane & 15);
                bf16x8 afrag = *(const bf16x8*)(As + row * 64 + ((ci ^ (row & 7)) * 8));
                acc[m] = __builtin_amdgcn_mfma_f32_16x16x32_bf16(afrag, bfrag, acc[m], 0, 0, 0);
            }
        }
        __syncthreads();
    }
    int col = n0 + wid * 16 + (lane & 15);
    #pragma unroll
    for (int m = 0; m < 4; ++m) {
        int rb = m * 16 + (lane >> 4) * 4;
        #pragma unroll
        for (int r = 0; r < 4; ++r)
            pawe[((size_t)kc * BB + rb + r) * 2048 + col] = acc[m][r];
    }
}

// P4: LSTM pointwise + memory attention + carry; grid 64
__global__ __launch_bounds__(256) void k_p4(const float* __restrict__ hhp,
        const float* __restrict__ pawe, const float* __restrict__ xpre,
        const float* __restrict__ bih, const float* __restrict__ bhh,
        const int* __restrict__ lens, int t, const float* __restrict__ memB,
        float* __restrict__ h, float* __restrict__ c,
        ushort* __restrict__ hB, ushort* __restrict__ histB) {
    __shared__ float hss[512], simss[128], reds[256], pss[128];
    const int b = blockIdx.x, tid = threadIdx.x;
    const int lane = tid & 63, wid = tid >> 6;
    bool msk = t < (lens[b] - 1);
    for (int j = tid; j < 512; j += 256) {
        float g[4];
        #pragma unroll
        for (int q = 0; q < 4; ++q) {
            int col = q * 512 + j;
            float s = bih[col] + bhh[col]
                    + hhp[(size_t)b * 2048 + col]
                    + xpre[((size_t)t * BB + b) * 2048 + col];
            #pragma unroll
            for (int kc = 0; kc < 4; ++kc) s += pawe[((size_t)kc * BB + b) * 2048 + col];
            g[q] = s;
        }
        float gi = sigm(g[0]), gf = sigm(g[1]), gg = tanh_f(g[2]), go = sigm(g[3]);
        float cold = c[b * 512 + j];
        float cn = gf * cold + gi * gg;
        c[b * 512 + j] = msk ? cn : cold;
        hss[j] = go * tanh_f(cn);
    }
    __syncthreads();
    for (int m = wid * 32; m < wid * 32 + 32; ++m) {
        const float* r = memB + (size_t)m * 512 + lane * 8;
        float4 r0 = *(const float4*)(r);
        float4 r1 = *(const float4*)(r + 4);
        float4 h0 = *(const float4*)(&hss[lane * 8]);
        float4 h1 = *(const float4*)(&hss[lane * 8 + 4]);
        float s = r0.x * h0.x + r0.y * h0.y + r0.z * h0.z + r0.w * h0.w
                + r1.x * h1.x + r1.y * h1.y + r1.z * h1.z + r1.w * h1.w;
        #pragma unroll
        for (int off = 32; off; off >>= 1) s += __shfl_down(s, off);
        if (lane == 0) simss[m] = s;
    }
    __syncthreads();
    float v = (tid < 128) ? simss[tid] : -3.4e38f;
    reds[tid] = v; __syncthreads();
    for (int s = 128; s; s >>= 1) { if (tid < s) reds[tid] = fmaxf(reds[tid], reds[tid + s]); __syncthreads(); }
    float mx = reds[0]; __syncthreads();
    float ev = (tid < 128) ? __expf(v - mx) : 0.f;
    reds[tid] = ev; __syncthreads();
    for (int s = 128; s; s >>= 1) { if (tid < s) reds[tid] += reds[tid + s]; __syncthreads(); }
    if (tid < 128) pss[tid] = ev / reds[0];
    __syncthreads();
    for (int d = tid; d < 512; d += 256) {
        float s = 0.f;
        #pragma unroll 4
        for (int m = 0; m < 128; ++m) s += pss[m] * memB[(size_t)m * 512 + d];
        float hn = hss[d] + s;
        histB[((size_t)t * BB + b) * 512 + d] = f2bf(hn);
        float hold = h[b * 512 + d];
        float hv = msk ? hn : hold;
        h[b * 512 + d] = hv;
        hB[b * 512 + d] = f2bf(hv);
    }
}

// batched preds: hist(21*64 x 512) @ WfcT^T + bfc, masked. grid (40, 21)
__global__ __launch_bounds__(256) void k_preds_batch(const ushort* __restrict__ histB,
        const ushort* __restrict__ WfcT, const float* __restrict__ bfc,
        const int* __restrict__ lens, float* __restrict__ out) {
    __shared__ alignas(16) ushort As[64 * 64];
    __shared__ alignas(16) ushort Bs[256 * 64];
    const int n0 = blockIdx.x * 256;
    const int t = blockIdx.y;
    const ushort* A = histB + (size_t)t * BB * 512;
    const int tid = threadIdx.x, wid = tid >> 6, lane = tid & 63;
    f32x4 acc[4][4] = {};
    for (int k0 = 0; k0 < 512; k0 += 64) {
        #pragma unroll
        for (int p = 0; p < 2; ++p) {
            int c = p * 256 + tid;
            int r = c >> 3, cc = c & 7;
            float4 v = *(const float4*)(A + r * 512 + k0 + cc * 8);
            *(float4*)(As + r * 64 + ((cc ^ (r & 7)) * 8)) = v;
        }
        #pragma unroll
        for (int p = 0; p < 8; ++p) {
            int c = p * 256 + tid;
            int r = c >> 3, cc = c & 7;
            float4 v = *(const float4*)(WfcT + (size_t)(n0 + r) * 512 + k0 + cc * 8);
            *(float4*)(Bs + r * 64 + ((cc ^ (r & 7)) * 8)) = v;
        }
        __syncthreads();
        #pragma unroll
        for (int kk = 0; kk < 2; ++kk) {
            int ci = kk * 4 + (lane >> 4);
            bf16x8 afrag[4], bfrag[4];
            #pragma unroll
            for (int m = 0; m < 4; ++m) {
                int row = m * 16 + (lane & 15);
                afrag[m] = *(const bf16x8*)(As + row * 64 + ((ci ^ (row & 7)) * 8));
            }
            #pragma unroll
            for (int n = 0; n < 4; ++n) {
                int col = wid * 64 + n * 16 + (lane & 15);
                bfrag[n] = *(const bf16x8*)(Bs + col * 64 + ((ci ^ (col & 7)) * 8));
            }
            #pragma unroll
            for (int m = 0; m < 4; ++m)
                #pragma unroll
                for (int n = 0; n < 4; ++n)
                    acc[m][n] = __builtin_amdgcn_mfma_f32_16x16x32_bf16(afrag[m], bfrag[n], acc[m][n], 0, 0, 0);
        }
        __syncthreads();
    }
    #pragma unroll
    for (int m = 0; m < 4; ++m) {
        int rb = m * 16 + (lane >> 4) * 4;
        #pragma unroll
        for (int n = 0; n < 4; ++n) {
            int col = n0 + wid * 64 + n * 16 + (lane & 15);
            if (col < VV) {
                float bv = bfc[col];
                #pragma unroll
                for (int r = 0; r < 4; ++r) {
                    int b = rb + r;
                    bool msk = t < (lens[b] - 1);
                    out[((size_t)b * TT + t) * VV + col] = msk ? (acc[m][n][r] + bv) : 0.f;
                }
            }
        }
    }
}

// ---------------- launch ----------------

extern "C" void kernel_launch(void* const* d_in, const int* in_sizes, int n_in,
                              void* d_out, int out_size, void* d_ws, size_t ws_size,
                              hipStream_t stream) {
    const float* enc     = (const float*)d_in[0];
    const int*   caps    = (const int*)d_in[1];
    const int*   lens    = (const int*)d_in[2];
    const float* emb     = (const float*)d_in[3];
    const float* W_enc   = (const float*)d_in[4];
    const float* b_enc   = (const float*)d_in[5];
    const float* W_dec   = (const float*)d_in[6];
    const float* b_dec   = (const float*)d_in[7];
    const float* W_full  = (const float*)d_in[8];
    const float* W_inith = (const float*)d_in[10];
    const float* b_inith = (const float*)d_in[11];
    const float* W_initc = (const float*)d_in[12];
    const float* b_initc = (const float*)d_in[13];
    const float* W_beta  = (const float*)d_in[14];
    const float* b_beta  = (const float*)d_in[15];
    const float* W_ih    = (const float*)d_in[16];
    const float* b_ih    = (const float*)d_in[17];
    const float* W_hh    = (const float*)d_in[18];
    const float* b_hh    = (const float*)d_in[19];
    const float* memB    = (const float*)d_in[20];
    const float* W_fc    = (const float*)d_in[21];
    const float* b_fc    = (const float*)d_in[22];

    float* out = (float*)d_out;
    float* preds_out  = out;
    float* declen_out = out + (size_t)BB * TT * VV;
    float* alpha_out  = declen_out + BB;

    float* ws    = (float*)d_ws;
    ushort* att1B = (ushort*)ws;  ws += (size_t)12544 * 512 / 2;
    float* h     = ws;  ws += BB * DECD;
    float* c     = ws;  ws += BB * DECD;
    float* att2  = ws;  ws += BB * 512;
    float* gate  = ws;  ws += BB * 2048;
    float* hhp   = ws;  ws += BB * 2048;
    float* pawe  = ws;  ws += (size_t)4 * BB * 2048;
    float* xpre  = ws;  ws += (size_t)TT * BB * 2048;
    ushort* hB   = (ushort*)ws;  ws += BB * DECD / 2;
    uint*  aweB  = (uint*)ws;    ws += BB * 1024;
    ushort* histB = (ushort*)ws; ws += (size_t)TT * BB * DECD / 2;
    ushort* encB  = (ushort*)ws; ws += (size_t)12544 * 2048 / 2;
    uint*  enc8  = (uint*)ws;    ws += (size_t)12544 * 2048 / 4;
    ushort* WencT = (ushort*)ws; ws += (size_t)512 * 2048 / 2;
    ushort* WfcT  = (ushort*)ws; ws += (size_t)10240 * 512 / 2;
    ushort* WcatT = (ushort*)ws; ws += (size_t)4608 * 512 / 2;
    ushort* WihT  = (ushort*)ws; ws += (size_t)2048 * KIH / 2;
    // aliases (dead before their regions are written)
    float* mean  = (float*)att1B;   // dead before k_att1n
    float* ipart = xpre;            // dead before k_xpre

    k_cvt2<<<(12544 * 2048 / 4 + 255) / 256, 256, 0, stream>>>(enc, encB, enc8, 12544 * 2048 / 4);
    k_mean16<<<256, 256, 0, stream>>>(encB, mean);
    k_ipart<<<dim3(8, 4, 2), 256, 0, stream>>>(mean, W_inith, W_initc, ipart);
    k_ifin<<<256, 256, 0, stream>>>(ipart, b_inith, b_initc, h, c, hB);
    k_declen<<<1, 64, 0, stream>>>(lens, declen_out);
    k_tcvt_all<<<3392, 256, 0, stream>>>(W_enc, W_dec, W_beta, W_hh, W_ih, W_fc,
                                         WencT, WcatT, WcatT + (size_t)512 * 512,
                                         WcatT + (size_t)2560 * 512, WihT, WfcT);
    k_att1n<<<dim3(2, 196), 256, 0, stream>>>(encB, WencT, b_enc, att1B);
    k_xpre<<<dim3(8, TT), 256, 0, stream>>>(emb, caps, WihT, xpre);

    for (int t = 0; t < TT; ++t) {
        k_p1<<<72, 256, 0, stream>>>(hB, WcatT, b_dec, b_beta, att2, gate, hhp);
        k_esawe<<<64, 256, 0, stream>>>(att1B, att2, W_full, enc8, gate, lens, t, aweB, alpha_out);
        k_p3<<<128, 256, 0, stream>>>(aweB, WihT, pawe);
        k_p4<<<64, 256, 0, stream>>>(hhp, pawe, xpre, b_ih, b_hh, lens, t, memB, h, c, hB, histB);
    }

    k_preds_batch<<<dim3(40, TT), 256, 0, stream>>>(histB, WfcT, b_fc, lens, preds_out);
}

// Round 17
// 1649.924 us; speedup vs baseline: 1.4121x; 1.4121x over previous
//
#include <hip/hip_runtime.h>

#define BB   64
#define PP   196
#define ENCD 2048
#define DECD 512
#define VV   10000
#define TT   21
#define KIH  2560   // (EMB + ENC) rows of W_ih

typedef __attribute__((ext_vector_type(8))) short bf16x8;
typedef __attribute__((ext_vector_type(4))) float f32x4;
typedef float f32x2 __attribute__((ext_vector_type(2)));

__device__ __forceinline__ float sigm(float x)   { return 1.f / (1.f + __expf(-x)); }
__device__ __forceinline__ float tanh_f(float x) { return 1.f - 2.f / (1.f + __expf(2.f * x)); }
__device__ __forceinline__ ushort f2bf(float x) {
    unsigned u = __float_as_uint(x);
    unsigned r = (u + 0x7FFFu + ((u >> 16) & 1u)) >> 16;
    return (ushort)r;
}
__device__ __forceinline__ float bf2f(ushort u) {
    return __uint_as_float(((unsigned)u) << 16);
}
union U8 { float4 f4; ushort u[8]; };

// ---- fp8 helpers (HW cvt when available; self-consistent SW fallback) ----
#if __has_builtin(__builtin_amdgcn_cvt_pk_fp8_f32) && __has_builtin(__builtin_amdgcn_cvt_pk_f32_fp8)
#define HAVE_HW_FP8 1
#endif

__device__ uint enc8m(float x) {     // e4m3fn round-to-nearest (fallback only)
    uint s = (__float_as_uint(x) >> 31) << 7;
    float ax = fabsf(x);
    if (!(ax > 0.f)) return s;
    if (ax >= 448.f) return s | 0x7e;
    int e; float m = frexpf(ax, &e);
    int E = e - 1 + 7;
    if (E <= 0) { int q = (int)rintf(ax * 512.f); if (q > 7) return s | 0x08; return s | (uint)q; }
    int q = (int)rintf((m * 2.f - 1.f) * 8.f);
    if (q == 8) { q = 0; ++E; if (E > 15) return s | 0x7e; }
    return s | ((uint)E << 3) | (uint)q;
}
__device__ __forceinline__ float dec8m(uint b) {
    uint s = b >> 7, e = (b >> 3) & 15, m = b & 7;
    float v = (e == 0) ? (float)m * (1.f / 512.f) : ldexpf(1.f + (float)m * 0.125f, (int)e - 7);
    return s ? -v : v;
}
__device__ __forceinline__ uint pkfp8x4(float a, float b, float c, float d) {
#ifdef HAVE_HW_FP8
    int v = __builtin_amdgcn_cvt_pk_fp8_f32(a, b, 0, false);
    v = __builtin_amdgcn_cvt_pk_fp8_f32(c, d, v, true);
    return (uint)v;
#else
    return enc8m(a) | (enc8m(b) << 8) | (enc8m(c) << 16) | (enc8m(d) << 24);
#endif
}
__device__ __forceinline__ void dec8x4(uint v, float out[4]) {
#ifdef HAVE_HW_FP8
    f32x2 lo = __builtin_amdgcn_cvt_pk_f32_fp8((int)v, false);
    f32x2 hi = __builtin_amdgcn_cvt_pk_f32_fp8((int)v, true);
    out[0] = lo[0]; out[1] = lo[1]; out[2] = hi[0]; out[3] = hi[1];
#else
    out[0] = dec8m(v & 255); out[1] = dec8m((v >> 8) & 255);
    out[2] = dec8m((v >> 16) & 255); out[3] = dec8m(v >> 24);
#endif
}

// ---------------- setup kernels ----------------

// fused: f32 -> bf16 AND fp8x4 in one pass over enc
__global__ void k_cvt2(const float* __restrict__ in, ushort* __restrict__ outB,
                       uint* __restrict__ out8, int n4) {
    int i = blockIdx.x * 256 + threadIdx.x;
    if (i >= n4) return;
    float4 v = ((const float4*)in)[i];
    ushort4 o; o.x = f2bf(v.x); o.y = f2bf(v.y); o.z = f2bf(v.z); o.w = f2bf(v.w);
    ((ushort4*)outB)[i] = o;
    out8[i] = pkfp8x4(v.x, v.y, v.z, v.w);
}

__global__ void k_mean16(const ushort* __restrict__ encB, float* __restrict__ mean) {
    int idx = blockIdx.x * 256 + threadIdx.x;
    int b = idx >> 10, e2 = idx & 1023;
    const uint* p = (const uint*)encB + (size_t)b * PP * 1024 + e2;
    float s0 = 0.f, s1 = 0.f;
    #pragma unroll 7
    for (int i = 0; i < PP; ++i) {
        uint v = p[(size_t)i * 1024];
        s0 += __uint_as_float(v << 16);
        s1 += __uint_as_float(v & 0xffff0000u);
    }
    mean[b * 2048 + e2 * 2]     = s0 * (1.f / 196.f);
    mean[b * 2048 + e2 * 2 + 1] = s1 * (1.f / 196.f);
}

__global__ __launch_bounds__(256) void k_ipart(const float* __restrict__ mean,
        const float* __restrict__ Wh, const float* __restrict__ Wc,
        float* __restrict__ ipart) {
    __shared__ alignas(16) float As[32][68];
    __shared__ alignas(16) float Bs[32][68];
    const int n0 = blockIdx.x * 64;
    const int kc = blockIdx.y;
    const int mat = blockIdx.z;
    const float* Bp = mat ? Wc : Wh;
    const int tid = threadIdx.x, tx = tid & 15, ty = tid >> 4;
    float acc[4][4] = {};
    for (int k0 = 0; k0 < 512; k0 += 32) {
        #pragma unroll
        for (int p = 0; p < 2; ++p) {
            int c = p * 256 + tid;
            int m = c >> 3, k4 = (c & 7) * 4;
            float4 v = *(const float4*)(mean + m * 2048 + kc * 512 + k0 + k4);
            As[k4 + 0][m] = v.x; As[k4 + 1][m] = v.y; As[k4 + 2][m] = v.z; As[k4 + 3][m] = v.w;
            int kb = c >> 4, n4 = (c & 15) * 4;
            float4 w = *(const float4*)(Bp + (size_t)(kc * 512 + k0 + kb) * 512 + n0 + n4);
            *(float4*)&Bs[kb][n4] = w;
        }
        __syncthreads();
        #pragma unroll 8
        for (int k = 0; k < 32; ++k) {
            float4 a = *(const float4*)&As[k][ty * 4];
            float4 b = *(const float4*)&Bs[k][tx * 4];
            float av[4] = {a.x, a.y, a.z, a.w}, bv[4] = {b.x, b.y, b.z, b.w};
            #pragma unroll
            for (int i = 0; i < 4; ++i)
                #pragma unroll
                for (int j = 0; j < 4; ++j) acc[i][j] += av[i] * bv[j];
        }
        __syncthreads();
    }
    #pragma unroll
    for (int i = 0; i < 4; ++i) {
        int m = ty * 4 + i;
        #pragma unroll
        for (int j = 0; j < 4; ++j) {
            int n = n0 + tx * 4 + j;
            ipart[((size_t)(mat * 4 + kc) * BB + m) * 512 + n] = acc[i][j];
        }
    }
}

__global__ void k_ifin(const float* __restrict__ ipart,
                       const float* __restrict__ bh, const float* __restrict__ bc,
                       float* __restrict__ h, float* __restrict__ c, ushort* __restrict__ hB) {
    int idx = blockIdx.x * 256 + threadIdx.x;
    int mat = idx >> 15, rem = idx & 32767;
    int b = rem >> 9, d = rem & 511;
    float s = 0.f;
    #pragma unroll
    for (int kc = 0; kc < 4; ++kc) s += ipart[((size_t)(mat * 4 + kc) * BB + b) * 512 + d];
    if (mat) c[rem] = s + bc[d];
    else { float v = s + bh[d]; h[rem] = v; hB[rem] = f2bf(v); }
}

__global__ __launch_bounds__(256) void k_tcvt_all(
        const float* __restrict__ Wenc, const float* __restrict__ Wdec,
        const float* __restrict__ Wbeta, const float* __restrict__ Whh,
        const float* __restrict__ Wih, const float* __restrict__ Wfc,
        ushort* __restrict__ WencT, ushort* __restrict__ WdecT,
        ushort* __restrict__ WbetaT, ushort* __restrict__ WhhT,
        ushort* __restrict__ WihT, ushort* __restrict__ WfcT) {
    __shared__ float lds[64 * 65];
    int l = blockIdx.x;
    const float* in; ushort* out; int K, N, KT;
    if (l < 256)       { in = Wenc;  out = WencT;  K = 2048; N = 512;   KT = 32; }
    else if (l < 320)  { l -= 256;  in = Wdec;  out = WdecT;  K = 512;  N = 512;   KT = 8; }
    else if (l < 576)  { l -= 320;  in = Wbeta; out = WbetaT; K = 512;  N = 2048;  KT = 8; }
    else if (l < 832)  { l -= 576;  in = Whh;   out = WhhT;   K = 512;  N = 2048;  KT = 8; }
    else if (l < 2112) { l -= 832;  in = Wih;   out = WihT;   K = KIH;  N = 2048;  KT = 40; }
    else               { l -= 2112; in = Wfc;   out = WfcT;   K = 512;  N = 10000; KT = 8; }
    const int k0 = (l % KT) * 64, n0 = (l / KT) * 64;
    const int tid = threadIdx.x;
    for (int i = tid; i < 4096; i += 256) {
        int kk = i >> 6, nn = i & 63;
        float v = 0.f;
        if (n0 + nn < N) v = in[(size_t)(k0 + kk) * N + n0 + nn];
        lds[nn * 65 + kk] = v;
    }
    __syncthreads();
    for (int i = tid; i < 4096; i += 256) {
        int nn = i >> 6, kk = i & 63;
        out[(size_t)(n0 + nn) * K + k0 + kk] = f2bf(lds[nn * 65 + kk]);
    }
}

// att1B[12544][512] bf16 = bf16(encB @ WencT^T + bias). grid (2, 196)
__global__ __launch_bounds__(256) void k_att1n(const ushort* __restrict__ A,
        const ushort* __restrict__ Bt, const float* __restrict__ bias,
        ushort* __restrict__ C) {
    __shared__ alignas(16) ushort As[64 * 64];
    __shared__ alignas(16) ushort Bs[256 * 64];
    const int n0 = blockIdx.x * 256;
    const int m0 = blockIdx.y * 64;
    const int tid = threadIdx.x, wid = tid >> 6, lane = tid & 63;
    f32x4 acc[4][4] = {};
    for (int k0 = 0; k0 < 2048; k0 += 64) {
        #pragma unroll
        for (int p = 0; p < 2; ++p) {
            int c = p * 256 + tid;
            int r = c >> 3, cc = c & 7;
            float4 v = *(const float4*)(A + (size_t)(m0 + r) * 2048 + k0 + cc * 8);
            *(float4*)(As + r * 64 + ((cc ^ (r & 7)) * 8)) = v;
        }
        #pragma unroll
        for (int p = 0; p < 8; ++p) {
            int c = p * 256 + tid;
            int r = c >> 3, cc = c & 7;
            float4 v = *(const float4*)(Bt + (size_t)(n0 + r) * 2048 + k0 + cc * 8);
            *(float4*)(Bs + r * 64 + ((cc ^ (r & 7)) * 8)) = v;
        }
        __syncthreads();
        #pragma unroll
        for (int kk = 0; kk < 2; ++kk) {
            int ci = kk * 4 + (lane >> 4);
            bf16x8 afrag[4], bfrag[4];
            #pragma unroll
            for (int m = 0; m < 4; ++m) {
                int row = m * 16 + (lane & 15);
                afrag[m] = *(const bf16x8*)(As + row * 64 + ((ci ^ (row & 7)) * 8));
            }
            #pragma unroll
            for (int n = 0; n < 4; ++n) {
                int col = wid * 64 + n * 16 + (lane & 15);
                bfrag[n] = *(const bf16x8*)(Bs + col * 64 + ((ci ^ (col & 7)) * 8));
            }
            #pragma unroll
            for (int m = 0; m < 4; ++m)
                #pragma unroll
                for (int n = 0; n < 4; ++n)
                    acc[m][n] = __builtin_amdgcn_mfma_f32_16x16x32_bf16(afrag[m], bfrag[n], acc[m][n], 0, 0, 0);
        }
        __syncthreads();
    }
    #pragma unroll
    for (int m = 0; m < 4; ++m) {
        int rb = m0 + m * 16 + (lane >> 4) * 4;
        #pragma unroll
        for (int n = 0; n < 4; ++n) {
            int col = n0 + wid * 64 + n * 16 + (lane & 15);
            float bv = bias[col];
            #pragma unroll
            for (int r = 0; r < 4; ++r)
                C[(size_t)(rb + r) * 512 + col] = f2bf(acc[m][n][r] + bv);
        }
    }
}

// xpre[t][b][2048] = emb[caps[b,t]] @ W_ih[0:512]. grid (8, 21)
__global__ __launch_bounds__(256) void k_xpre(const float* __restrict__ emb,
        const int* __restrict__ caps, const ushort* __restrict__ WihT,
        float* __restrict__ xpre) {
    __shared__ alignas(16) ushort As[64 * 64];
    __shared__ alignas(16) ushort Bs[256 * 64];
    __shared__ int capsh[64];
    const int n0 = blockIdx.x * 256;
    const int t = blockIdx.y;
    const int tid = threadIdx.x, wid = tid >> 6, lane = tid & 63;
    if (tid < 64) capsh[tid] = caps[tid * 22 + t];
    __syncthreads();
    f32x4 acc[4][4] = {};
    for (int k0 = 0; k0 < 512; k0 += 64) {
        #pragma unroll
        for (int p = 0; p < 2; ++p) {
            int c = p * 256 + tid;
            int r = c >> 3, cc = c & 7;
            const float* er = emb + (size_t)capsh[r] * 512 + k0 + cc * 8;
            float4 v0 = *(const float4*)er;
            float4 v1 = *(const float4*)(er + 4);
            U8 pk;
            pk.u[0] = f2bf(v0.x); pk.u[1] = f2bf(v0.y); pk.u[2] = f2bf(v0.z); pk.u[3] = f2bf(v0.w);
            pk.u[4] = f2bf(v1.x); pk.u[5] = f2bf(v1.y); pk.u[6] = f2bf(v1.z); pk.u[7] = f2bf(v1.w);
            *(float4*)(As + r * 64 + ((cc ^ (r & 7)) * 8)) = pk.f4;
        }
        #pragma unroll
        for (int p = 0; p < 8; ++p) {
            int c = p * 256 + tid;
            int r = c >> 3, cc = c & 7;
            float4 v = *(const float4*)(WihT + (size_t)(n0 + r) * KIH + k0 + cc * 8);
            *(float4*)(Bs + r * 64 + ((cc ^ (r & 7)) * 8)) = v;
        }
        __syncthreads();
        #pragma unroll
        for (int kk = 0; kk < 2; ++kk) {
            int ci = kk * 4 + (lane >> 4);
            bf16x8 afrag[4], bfrag[4];
            #pragma unroll
            for (int m = 0; m < 4; ++m) {
                int row = m * 16 + (lane & 15);
                afrag[m] = *(const bf16x8*)(As + row * 64 + ((ci ^ (row & 7)) * 8));
            }
            #pragma unroll
            for (int n = 0; n < 4; ++n) {
                int col = wid * 64 + n * 16 + (lane & 15);
                bfrag[n] = *(const bf16x8*)(Bs + col * 64 + ((ci ^ (col & 7)) * 8));
            }
            #pragma unroll
            for (int m = 0; m < 4; ++m)
                #pragma unroll
                for (int n = 0; n < 4; ++n)
                    acc[m][n] = __builtin_amdgcn_mfma_f32_16x16x32_bf16(afrag[m], bfrag[n], acc[m][n], 0, 0, 0);
        }
        __syncthreads();
    }
    #pragma unroll
    for (int m = 0; m < 4; ++m) {
        int rb = m * 16 + (lane >> 4) * 4;
        #pragma unroll
        for (int n = 0; n < 4; ++n) {
            int col = n0 + wid * 64 + n * 16 + (lane & 15);
            #pragma unroll
            for (int r = 0; r < 4; ++r)
                xpre[((size_t)t * BB + rb + r) * 2048 + col] = acc[m][n][r];
        }
    }
}

__global__ void k_declen(const int* __restrict__ lens, float* __restrict__ out) {
    int b = threadIdx.x;
    if (b < BB) out[b] = (float)(lens[b] - 1);
}

// ---------------- per-step kernels ----------------

// P1: att2|gate|hhp = hB @ WcatT (72 tiles of 64 cols, K=512)
__global__ __launch_bounds__(256) void k_p1(const ushort* __restrict__ hB,
        const ushort* __restrict__ WcatT, const float* __restrict__ bd,
        const float* __restrict__ bb, float* __restrict__ att2,
        float* __restrict__ gate, float* __restrict__ hhp) {
    __shared__ alignas(16) ushort As[64 * 64];
    __shared__ alignas(16) ushort Bs[64 * 64];
    const int tid = threadIdx.x, lane = tid & 63, wid = tid >> 6;
    const int n0 = blockIdx.x * 64;
    f32x4 acc[4] = {};
    for (int k0 = 0; k0 < 512; k0 += 64) {
        #pragma unroll
        for (int p = 0; p < 2; ++p) {
            int c8 = p * 256 + tid;
            int r = c8 >> 3, cc = c8 & 7;
            float4 v = *(const float4*)(hB + r * 512 + k0 + cc * 8);
            *(float4*)(As + r * 64 + ((cc ^ (r & 7)) * 8)) = v;
            float4 w = *(const float4*)(WcatT + (size_t)(n0 + r) * 512 + k0 + cc * 8);
            *(float4*)(Bs + r * 64 + ((cc ^ (r & 7)) * 8)) = w;
        }
        __syncthreads();
        #pragma unroll
        for (int kk = 0; kk < 2; ++kk) {
            int ci = kk * 4 + (lane >> 4);
            int colL = wid * 16 + (lane & 15);
            bf16x8 bfrag = *(const bf16x8*)(Bs + colL * 64 + ((ci ^ (colL & 7)) * 8));
            #pragma unroll
            for (int m = 0; m < 4; ++m) {
                int row = m * 16 + (lane & 15);
                bf16x8 afrag = *(const bf16x8*)(As + row * 64 + ((ci ^ (row & 7)) * 8));
                acc[m] = __builtin_amdgcn_mfma_f32_16x16x32_bf16(afrag, bfrag, acc[m], 0, 0, 0);
            }
        }
        __syncthreads();
    }
    int col = n0 + wid * 16 + (lane & 15);
    #pragma unroll
    for (int m = 0; m < 4; ++m) {
        int rb = m * 16 + (lane >> 4) * 4;
        #pragma unroll
        for (int r = 0; r < 4; ++r) {
            int row = rb + r;
            float v = acc[m][r];
            if (col < 512)       att2[row * 512 + col] = v + bd[col];
            else if (col < 2560) gate[row * 2048 + (col - 512)] = sigm(v + bb[col - 512]);
            else                 hhp[(size_t)row * 2048 + (col - 2560)] = v;
        }
    }
}

// P2a: e-score partial dot products; grid (4, 64), row-major att1B
__global__ __launch_bounds__(256) void k_escore_p(const ushort* __restrict__ att1B,
        const float* __restrict__ att2, const float* __restrict__ Wf,
        float* __restrict__ es) {
    __shared__ float a2[512], wf[512];
    int b = blockIdx.y, pc = blockIdx.x, tid = threadIdx.x;
    for (int i = tid; i < 512; i += 256) { a2[i] = att2[b * 512 + i]; wf[i] = Wf[i]; }
    __syncthreads();
    int lane = tid & 63, wid = tid >> 6;
    for (int i = wid; i < 49; i += 4) {
        int p = pc * 49 + i;
        bf16x8 rv = *(const bf16x8*)(att1B + ((size_t)(b * PP + p)) * 512 + lane * 8);
        float s = 0.f;
        #pragma unroll
        for (int j = 0; j < 8; ++j) {
            float v = bf2f((ushort)rv[j]) + a2[lane * 8 + j];
            s += (v > 0.f ? v : 0.f) * wf[lane * 8 + j];
        }
        #pragma unroll
        for (int off = 32; off; off >>= 1) s += __shfl_down(s, off);
        if (lane == 0) es[b * 256 + p] = s;
    }
}

// P2b: softmax + awe (fp8 enc) + gate + pack; grid (8, 64)
__global__ __launch_bounds__(256) void k_awe8(const uint* __restrict__ enc8,
        const float* __restrict__ es, const float* __restrict__ gate,
        const int* __restrict__ lens, int t,
        uint* __restrict__ aweB, float* __restrict__ alpha_out) {
    __shared__ float al[224], red[256], ps[4][64][4];
    int b = blockIdx.y, ec = blockIdx.x, tid = threadIdx.x;
    float v = (tid < PP) ? es[b * 256 + tid] : -3.4e38f;
    red[tid] = v; __syncthreads();
    for (int s = 128; s; s >>= 1) { if (tid < s) red[tid] = fmaxf(red[tid], red[tid + s]); __syncthreads(); }
    float mx = red[0]; __syncthreads();
    float ev = (tid < PP) ? __expf(v - mx) : 0.f;
    red[tid] = ev; __syncthreads();
    for (int s = 128; s; s >>= 1) { if (tid < s) red[tid] += red[tid + s]; __syncthreads(); }
    float inv = 1.f / red[0];
    if (tid < PP) {
        float a = ev * inv;
        al[tid] = a;
        if (ec == 0) {
            bool m = t < (lens[b] - 1);
            alpha_out[((size_t)b * TT + t) * PP + tid] = m ? a : 0.f;
        }
    }
    __syncthreads();
    int w = tid >> 6, lane = tid & 63;
    int quad = ec * 64 + lane;                       // 0..511, covers 4 elems each
    const uint* pp = enc8 + (size_t)b * PP * 512 + quad;
    float s0 = 0.f, s1 = 0.f, s2 = 0.f, s3 = 0.f;
    #pragma unroll 7
    for (int p = w; p < PP; p += 4) {
        uint vv = pp[(size_t)p * 512];
        float d[4]; dec8x4(vv, d);
        float a = al[p];
        s0 += a * d[0]; s1 += a * d[1]; s2 += a * d[2]; s3 += a * d[3];
    }
    ps[w][lane][0] = s0; ps[w][lane][1] = s1; ps[w][lane][2] = s2; ps[w][lane][3] = s3;
    __syncthreads();
    if (tid < 64) {
        float t0 = ps[0][tid][0] + ps[1][tid][0] + ps[2][tid][0] + ps[3][tid][0];
        float t1 = ps[0][tid][1] + ps[1][tid][1] + ps[2][tid][1] + ps[3][tid][1];
        float t2 = ps[0][tid][2] + ps[1][tid][2] + ps[2][tid][2] + ps[3][tid][2];
        float t3 = ps[0][tid][3] + ps[1][tid][3] + ps[2][tid][3] + ps[3][tid][3];
        int q2 = ec * 64 + tid;
        int e = q2 * 4;
        float g0 = t0 * gate[b * 2048 + e + 0];
        float g1 = t1 * gate[b * 2048 + e + 1];
        float g2 = t2 * gate[b * 2048 + e + 2];
        float g3 = t3 * gate[b * 2048 + e + 3];
        aweB[b * 1024 + q2 * 2]     = (uint)f2bf(g0) | ((uint)f2bf(g1) << 16);
        aweB[b * 1024 + q2 * 2 + 1] = (uint)f2bf(g2) | ((uint)f2bf(g3) << 16);
    }
}

// P3: pawe[kc] = aweB slice @ W_ih slice; grid 128
__global__ __launch_bounds__(256) void k_p3(const uint* __restrict__ aweB,
        const ushort* __restrict__ WihT, float* __restrict__ pawe) {
    __shared__ alignas(16) ushort As[64 * 64];
    __shared__ alignas(16) ushort Bs[64 * 64];
    const int tid = threadIdx.x, lane = tid & 63, wid = tid >> 6;
    const int n0 = (blockIdx.x & 31) * 64, kc = blockIdx.x >> 5;
    const ushort* aweU = (const ushort*)aweB;
    f32x4 acc[4] = {};
    for (int k0 = 0; k0 < 512; k0 += 64) {
        #pragma unroll
        for (int p = 0; p < 2; ++p) {
            int c8 = p * 256 + tid;
            int r = c8 >> 3, cc = c8 & 7;
            float4 v = *(const float4*)(aweU + r * 2048 + kc * 512 + k0 + cc * 8);
            *(float4*)(As + r * 64 + ((cc ^ (r & 7)) * 8)) = v;
            float4 w = *(const float4*)(WihT + (size_t)(n0 + r) * KIH + 512 + kc * 512 + k0 + cc * 8);
            *(float4*)(Bs + r * 64 + ((cc ^ (r & 7)) * 8)) = w;
        }
        __syncthreads();
        #pragma unroll
        for (int kk = 0; kk < 2; ++kk) {
            int ci = kk * 4 + (lane >> 4);
            int colL = wid * 16 + (lane & 15);
            bf16x8 bfrag = *(const bf16x8*)(Bs + colL * 64 + ((ci ^ (colL & 7)) * 8));
            #pragma unroll
            for (int m = 0; m < 4; ++m) {
                int row = m * 16 + (lane & 15);
                bf16x8 afrag = *(const bf16x8*)(As + row * 64 + ((ci ^ (row & 7)) * 8));
                acc[m] = __builtin_amdgcn_mfma_f32_16x16x32_bf16(afrag, bfrag, acc[m], 0, 0, 0);
            }
        }
        __syncthreads();
    }
    int col = n0 + wid * 16 + (lane & 15);
    #pragma unroll
    for (int m = 0; m < 4; ++m) {
        int rb = m * 16 + (lane >> 4) * 4;
        #pragma unroll
        for (int r = 0; r < 4; ++r)
            pawe[((size_t)kc * BB + rb + r) * 2048 + col] = acc[m][r];
    }
}

// P4: LSTM pointwise + memory attention + carry; grid 64
__global__ __launch_bounds__(256) void k_p4(const float* __restrict__ hhp,
        const float* __restrict__ pawe, const float* __restrict__ xpre,
        const float* __restrict__ bih, const float* __restrict__ bhh,
        const int* __restrict__ lens, int t, const float* __restrict__ memB,
        float* __restrict__ h, float* __restrict__ c,
        ushort* __restrict__ hB, ushort* __restrict__ histB) {
    __shared__ float hss[512], simss[128], reds[256], pss[128];
    const int b = blockIdx.x, tid = threadIdx.x;
    const int lane = tid & 63, wid = tid >> 6;
    bool msk = t < (lens[b] - 1);
    for (int j = tid; j < 512; j += 256) {
        float g[4];
        #pragma unroll
        for (int q = 0; q < 4; ++q) {
            int col = q * 512 + j;
            float s = bih[col] + bhh[col]
                    + hhp[(size_t)b * 2048 + col]
                    + xpre[((size_t)t * BB + b) * 2048 + col];
            #pragma unroll
            for (int kc = 0; kc < 4; ++kc) s += pawe[((size_t)kc * BB + b) * 2048 + col];
            g[q] = s;
        }
        float gi = sigm(g[0]), gf = sigm(g[1]), gg = tanh_f(g[2]), go = sigm(g[3]);
        float cold = c[b * 512 + j];
        float cn = gf * cold + gi * gg;
        c[b * 512 + j] = msk ? cn : cold;
        hss[j] = go * tanh_f(cn);
    }
    __syncthreads();
    for (int m = wid * 32; m < wid * 32 + 32; ++m) {
        const float* r = memB + (size_t)m * 512 + lane * 8;
        float4 r0 = *(const float4*)(r);
        float4 r1 = *(const float4*)(r + 4);
        float4 h0 = *(const float4*)(&hss[lane * 8]);
        float4 h1 = *(const float4*)(&hss[lane * 8 + 4]);
        float s = r0.x * h0.x + r0.y * h0.y + r0.z * h0.z + r0.w * h0.w
                + r1.x * h1.x + r1.y * h1.y + r1.z * h1.z + r1.w * h1.w;
        #pragma unroll
        for (int off = 32; off; off >>= 1) s += __shfl_down(s, off);
        if (lane == 0) simss[m] = s;
    }
    __syncthreads();
    float v = (tid < 128) ? simss[tid] : -3.4e38f;
    reds[tid] = v; __syncthreads();
    for (int s = 128; s; s >>= 1) { if (tid < s) reds[tid] = fmaxf(reds[tid], reds[tid + s]); __syncthreads(); }
    float mx = reds[0]; __syncthreads();
    float ev = (tid < 128) ? __expf(v - mx) : 0.f;
    reds[tid] = ev; __syncthreads();
    for (int s = 128; s; s >>= 1) { if (tid < s) reds[tid] += reds[tid + s]; __syncthreads(); }
    if (tid < 128) pss[tid] = ev / reds[0];
    __syncthreads();
    for (int d = tid; d < 512; d += 256) {
        float s = 0.f;
        #pragma unroll 4
        for (int m = 0; m < 128; ++m) s += pss[m] * memB[(size_t)m * 512 + d];
        float hn = hss[d] + s;
        histB[((size_t)t * BB + b) * 512 + d] = f2bf(hn);
        float hold = h[b * 512 + d];
        float hv = msk ? hn : hold;
        h[b * 512 + d] = hv;
        hB[b * 512 + d] = f2bf(hv);
    }
}

// batched preds: hist(21*64 x 512) @ WfcT^T + bfc, masked. grid (40, 21)
__global__ __launch_bounds__(256) void k_preds_batch(const ushort* __restrict__ histB,
        const ushort* __restrict__ WfcT, const float* __restrict__ bfc,
        const int* __restrict__ lens, float* __restrict__ out) {
    __shared__ alignas(16) ushort As[64 * 64];
    __shared__ alignas(16) ushort Bs[256 * 64];
    const int n0 = blockIdx.x * 256;
    const int t = blockIdx.y;
    const ushort* A = histB + (size_t)t * BB * 512;
    const int tid = threadIdx.x, wid = tid >> 6, lane = tid & 63;
    f32x4 acc[4][4] = {};
    for (int k0 = 0; k0 < 512; k0 += 64) {
        #pragma unroll
        for (int p = 0; p < 2; ++p) {
            int c = p * 256 + tid;
            int r = c >> 3, cc = c & 7;
            float4 v = *(const float4*)(A + r * 512 + k0 + cc * 8);
            *(float4*)(As + r * 64 + ((cc ^ (r & 7)) * 8)) = v;
        }
        #pragma unroll
        for (int p = 0; p < 8; ++p) {
            int c = p * 256 + tid;
            int r = c >> 3, cc = c & 7;
            float4 v = *(const float4*)(WfcT + (size_t)(n0 + r) * 512 + k0 + cc * 8);
            *(float4*)(Bs + r * 64 + ((cc ^ (r & 7)) * 8)) = v;
        }
        __syncthreads();
        #pragma unroll
        for (int kk = 0; kk < 2; ++kk) {
            int ci = kk * 4 + (lane >> 4);
            bf16x8 afrag[4], bfrag[4];
            #pragma unroll
            for (int m = 0; m < 4; ++m) {
                int row = m * 16 + (lane & 15);
                afrag[m] = *(const bf16x8*)(As + row * 64 + ((ci ^ (row & 7)) * 8));
            }
            #pragma unroll
            for (int n = 0; n < 4; ++n) {
                int col = wid * 64 + n * 16 + (lane & 15);
                bfrag[n] = *(const bf16x8*)(Bs + col * 64 + ((ci ^ (col & 7)) * 8));
            }
            #pragma unroll
            for (int m = 0; m < 4; ++m)
                #pragma unroll
                for (int n = 0; n < 4; ++n)
                    acc[m][n] = __builtin_amdgcn_mfma_f32_16x16x32_bf16(afrag[m], bfrag[n], acc[m][n], 0, 0, 0);
        }
        __syncthreads();
    }
    #pragma unroll
    for (int m = 0; m < 4; ++m) {
        int rb = m * 16 + (lane >> 4) * 4;
        #pragma unroll
        for (int n = 0; n < 4; ++n) {
            int col = n0 + wid * 64 + n * 16 + (lane & 15);
            if (col < VV) {
                float bv = bfc[col];
                #pragma unroll
                for (int r = 0; r < 4; ++r) {
                    int b = rb + r;
                    bool msk = t < (lens[b] - 1);
                    out[((size_t)b * TT + t) * VV + col] = msk ? (acc[m][n][r] + bv) : 0.f;
                }
            }
        }
    }
}

// ---------------- launch ----------------

extern "C" void kernel_launch(void* const* d_in, const int* in_sizes, int n_in,
                              void* d_out, int out_size, void* d_ws, size_t ws_size,
                              hipStream_t stream) {
    const float* enc     = (const float*)d_in[0];
    const int*   caps    = (const int*)d_in[1];
    const int*   lens    = (const int*)d_in[2];
    const float* emb     = (const float*)d_in[3];
    const float* W_enc   = (const float*)d_in[4];
    const float* b_enc   = (const float*)d_in[5];
    const float* W_dec   = (const float*)d_in[6];
    const float* b_dec   = (const float*)d_in[7];
    const float* W_full  = (const float*)d_in[8];
    const float* W_inith = (const float*)d_in[10];
    const float* b_inith = (const float*)d_in[11];
    const float* W_initc = (const float*)d_in[12];
    const float* b_initc = (const float*)d_in[13];
    const float* W_beta  = (const float*)d_in[14];
    const float* b_beta  = (const float*)d_in[15];
    const float* W_ih    = (const float*)d_in[16];
    const float* b_ih    = (const float*)d_in[17];
    const float* W_hh    = (const float*)d_in[18];
    const float* b_hh    = (const float*)d_in[19];
    const float* memB    = (const float*)d_in[20];
    const float* W_fc    = (const float*)d_in[21];
    const float* b_fc    = (const float*)d_in[22];

    float* out = (float*)d_out;
    float* preds_out  = out;
    float* declen_out = out + (size_t)BB * TT * VV;
    float* alpha_out  = declen_out + BB;

    float* ws    = (float*)d_ws;
    ushort* att1B = (ushort*)ws;  ws += (size_t)12544 * 512 / 2;
    float* h     = ws;  ws += BB * DECD;
    float* c     = ws;  ws += BB * DECD;
    float* att2  = ws;  ws += BB * 512;
    float* gate  = ws;  ws += BB * 2048;
    float* hhp   = ws;  ws += BB * 2048;
    float* es    = ws;  ws += BB * 256;
    float* pawe  = ws;  ws += (size_t)4 * BB * 2048;
    float* xpre  = ws;  ws += (size_t)TT * BB * 2048;
    ushort* hB   = (ushort*)ws;  ws += BB * DECD / 2;
    uint*  aweB  = (uint*)ws;    ws += BB * 1024;
    ushort* histB = (ushort*)ws; ws += (size_t)TT * BB * DECD / 2;
    ushort* encB  = (ushort*)ws; ws += (size_t)12544 * 2048 / 2;
    uint*  enc8  = (uint*)ws;    ws += (size_t)12544 * 2048 / 4;
    ushort* WencT = (ushort*)ws; ws += (size_t)512 * 2048 / 2;
    ushort* WfcT  = (ushort*)ws; ws += (size_t)10240 * 512 / 2;
    ushort* WcatT = (ushort*)ws; ws += (size_t)4608 * 512 / 2;
    ushort* WihT  = (ushort*)ws; ws += (size_t)2048 * KIH / 2;
    // aliases (dead before their regions are written)
    float* mean  = (float*)att1B;   // dead before k_att1n
    float* ipart = xpre;            // dead before k_xpre

    k_cvt2<<<(12544 * 2048 / 4 + 255) / 256, 256, 0, stream>>>(enc, encB, enc8, 12544 * 2048 / 4);
    k_mean16<<<256, 256, 0, stream>>>(encB, mean);
    k_ipart<<<dim3(8, 4, 2), 256, 0, stream>>>(mean, W_inith, W_initc, ipart);
    k_ifin<<<256, 256, 0, stream>>>(ipart, b_inith, b_initc, h, c, hB);
    k_declen<<<1, 64, 0, stream>>>(lens, declen_out);
    k_tcvt_all<<<3392, 256, 0, stream>>>(W_enc, W_dec, W_beta, W_hh, W_ih, W_fc,
                                         WencT, WcatT, WcatT + (size_t)512 * 512,
                                         WcatT + (size_t)2560 * 512, WihT, WfcT);
    k_att1n<<<dim3(2, 196), 256, 0, stream>>>(encB, WencT, b_enc, att1B);
    k_xpre<<<dim3(8, TT), 256, 0, stream>>>(emb, caps, WihT, xpre);

    for (int t = 0; t < TT; ++t) {
        k_p1<<<72, 256, 0, stream>>>(hB, WcatT, b_dec, b_beta, att2, gate, hhp);
        k_escore_p<<<dim3(4, 64), 256, 0, stream>>>(att1B, att2, W_full, es);
        k_awe8<<<dim3(8, 64), 256, 0, stream>>>(enc8, es, gate, lens, t, aweB, alpha_out);
        k_p3<<<128, 256, 0, stream>>>(aweB, WihT, pawe);
        k_p4<<<64, 256, 0, stream>>>(hhp, pawe, xpre, b_ih, b_hh, lens, t, memB, h, c, hB, histB);
    }

    k_preds_batch<<<dim3(40, TT), 256, 0, stream>>>(histB, WfcT, b_fc, lens, preds_out);
}